// Round 8
// baseline (460.132 us; speedup 1.0000x reference)
//
#include <hip/hip_runtime.h>

constexpr int NCAMS   = 6;
constexpr int EMB     = 256;
constexpr int NGROUPS = 8;
constexpr int NLVL    = 4;
constexpr int NPTS    = 13;
constexpr int NPAIR   = NPTS * NCAMS;   // 78
constexpr int NWAVES  = 8;              // waves per block (512 threads)

// NOTE: min-waves hints are poison: (512,8) and (256,8) both made hipcc clamp
// to 32 VGPRs and spill ~2.4 GB to scratch (rounds 4/6). launch_bounds WITHOUT
// a min-waves arg lets the allocator pick ~64 VGPRs, zero spill.
// 512-thread packaging is the occupancy lever: 4-wave blocks plateaued at
// ~13.6 waves/CU (42%) regardless of grid size (rounds 2/7); round 4's
// 512-thread variant was the only one to show ~80% residency.
__global__ __launch_bounds__(512)
void dfa_kernel(const float* __restrict__ value,
                const int*   __restrict__ shapes,   // (6,4,2) — cam0 rows used
                const int*   __restrict__ starts,   // (6,4)
                const float* __restrict__ loc,      // (B,A,P,6,2)
                const float* __restrict__ attw,     // (B,A,P,6,4,8)
                float*       __restrict__ out,      // (B,A,256)
                int A, int per_cam)
{
    const int tid  = threadIdx.x;
    const int wv   = tid >> 6;      // wave id 0..7
    const int lane = tid & 63;
    const int b = blockIdx.x / A;
    const int a = blockIdx.x - b * A;

    __shared__ int   sH[NLVL], sW[NLVL], sS[NLVL];
    __shared__ float red[NWAVES][EMB];
    if (tid < NLVL) {
        sH[tid] = shapes[tid * 2 + 0];
        sW[tid] = shapes[tid * 2 + 1];
        sS[tid] = starts[tid];
    }
    __syncthreads();

    const int g = lane >> 3;        // group for channels 4*lane..4*lane+3
    const long ba = (long)b * A + a;
    const float* locp = loc  + ba * (NPTS * NCAMS * 2);
    const float* awp  = attw + ba * (NPTS * NCAMS * NLVL * NGROUPS) + g;

    float4 acc = make_float4(0.f, 0.f, 0.f, 0.f);

    for (int pair = wv; pair < NPAIR; pair += NWAVES) {
        const int p = pair / NCAMS;
        const int c = pair - p * NCAMS;
        const float lw = locp[pair * 2 + 0];
        const float lh = locp[pair * 2 + 1];
        const float* vb = value + ((long)(b * NCAMS + c) * per_cam) * EMB + lane * 4;
        const float* awpc = awp + pair * (NLVL * NGROUPS);

        #pragma unroll
        for (int lvl = 0; lvl < NLVL; ++lvl) {
            const int H = sH[lvl], W = sW[lvl], S = sS[lvl];
            const float hf = lh * (float)H - 0.5f;
            const float wf = lw * (float)W - 0.5f;
            const float h0f = floorf(hf), w0f = floorf(wf);
            const float dh = hf - h0f, dw = wf - w0f;
            const int h0 = (int)h0f, w0 = (int)w0f;
            const int h1 = h0 + 1,  w1 = w0 + 1;

            const float aw = awpc[lvl * NGROUPS];

            float w00 = (1.f - dh) * (1.f - dw) * aw;
            float w01 = (1.f - dh) * dw         * aw;
            float w10 = dh         * (1.f - dw) * aw;
            float w11 = dh         * dw         * aw;

            const bool vh0 = (unsigned)h0 < (unsigned)H;
            const bool vh1 = (unsigned)h1 < (unsigned)H;
            const bool vw0 = (unsigned)w0 < (unsigned)W;
            const bool vw1 = (unsigned)w1 < (unsigned)W;
            w00 = (vh0 && vw0) ? w00 : 0.f;
            w01 = (vh0 && vw1) ? w01 : 0.f;
            w10 = (vh1 && vw0) ? w10 : 0.f;
            w11 = (vh1 && vw1) ? w11 : 0.f;

            const int h0c = min(max(h0, 0), H - 1);
            const int h1c = min(max(h1, 0), H - 1);
            const int w0c = min(max(w0, 0), W - 1);
            const int w1c = min(max(w1, 0), W - 1);

            const float* r0 = vb + (long)(S + h0c * W) * EMB;
            const float* r1 = vb + (long)(S + h1c * W) * EMB;

            const float4 v00 = *(const float4*)(r0 + (long)w0c * EMB);
            const float4 v01 = *(const float4*)(r0 + (long)w1c * EMB);
            const float4 v10 = *(const float4*)(r1 + (long)w0c * EMB);
            const float4 v11 = *(const float4*)(r1 + (long)w1c * EMB);

            acc.x += v00.x * w00 + v01.x * w01 + v10.x * w10 + v11.x * w11;
            acc.y += v00.y * w00 + v01.y * w01 + v10.y * w10 + v11.y * w11;
            acc.z += v00.z * w00 + v01.z * w01 + v10.z * w10 + v11.z * w11;
            acc.w += v00.w * w00 + v01.w * w01 + v10.w * w10 + v11.w * w11;
        }
    }

    *(float4*)&red[wv][lane * 4] = acc;
    __syncthreads();

    if (tid < EMB) {
        float o = red[0][tid];
        #pragma unroll
        for (int w = 1; w < NWAVES; ++w) o += red[w][tid];
        out[ba * EMB + tid] = o;
    }
}

extern "C" void kernel_launch(void* const* d_in, const int* in_sizes, int n_in,
                              void* d_out, int out_size, void* d_ws, size_t ws_size,
                              hipStream_t stream) {
    const float* value  = (const float*)d_in[0];
    const int*   shapes = (const int*)d_in[1];
    const int*   starts = (const int*)d_in[2];
    const float* loc    = (const float*)d_in[3];
    const float* attw   = (const float*)d_in[4];
    float*       out    = (float*)d_out;

    const int B = 2;
    const int A = out_size / (EMB * B);                  // 900
    const int per_cam = in_sizes[0] / (B * EMB * NCAMS); // 14960

    dim3 grid(B * A);
    dim3 block(512);
    dfa_kernel<<<grid, block, 0, stream>>>(value, shapes, starts, loc, attw, out,
                                           A, per_cam);
}

// Round 9
// 444.987 us; speedup vs baseline: 1.0340x; 1.0340x over previous
//
#include <hip/hip_runtime.h>

constexpr int NCAMS   = 6;
constexpr int EMB     = 256;
constexpr int NGROUPS = 8;
constexpr int NLVL    = 4;
constexpr int NPTS    = 13;
constexpr int NPAIR   = NPTS * NCAMS;   // 78
constexpr int NWAVES  = 8;              // waves per block (512 threads)

// Settled facts (rounds 2-8):
//  - min-waves hints ((512,8),(256,8)) force VGPR=32 + ~2.4 GB scratch spill.
//  - occupancy pins at ~13 waves/CU (42%) for every non-spilled packaging;
//    resident-wave count is NOT the available lever.
//  - fetch BW pins at ~3.3 TB/s, VALUBusy ~22%: latency-bound, not BW-bound.
// This version attacks per-wave MLP: 2-deep register double-buffer over
// (point,cam) pairs so 16 corner loads are always in flight during FMAs.

__device__ __forceinline__ void issue_pair(
    int pair,
    const float* __restrict__ value,
    const float* __restrict__ locp,
    const float* __restrict__ awp_g,
    int b, int per_cam, int lane,
    const int H_[NLVL], const int W_[NLVL], const int S_[NLVL],
    float4 d[16], float wg[16])
{
    const int p = pair / NCAMS;
    const int c = pair - p * NCAMS;
    const float lw = locp[pair * 2 + 0];
    const float lh = locp[pair * 2 + 1];
    const float* vb = value + ((long)(b * NCAMS + c) * per_cam) * EMB + lane * 4;
    const float* awpc = awp_g + pair * (NLVL * NGROUPS);

    #pragma unroll
    for (int lvl = 0; lvl < NLVL; ++lvl) {
        const int H = H_[lvl], W = W_[lvl], S = S_[lvl];
        const float hf = lh * (float)H - 0.5f;
        const float wf = lw * (float)W - 0.5f;
        const float h0f = floorf(hf), w0f = floorf(wf);
        const float dh = hf - h0f, dw = wf - w0f;
        const int h0 = (int)h0f, w0 = (int)w0f;
        const int h1 = h0 + 1,  w1 = w0 + 1;

        const float aw = awpc[lvl * NGROUPS];

        const float w00 = (1.f - dh) * (1.f - dw) * aw;
        const float w01 = (1.f - dh) * dw         * aw;
        const float w10 = dh         * (1.f - dw) * aw;
        const float w11 = dh         * dw         * aw;

        const bool vh0 = (unsigned)h0 < (unsigned)H;
        const bool vh1 = (unsigned)h1 < (unsigned)H;
        const bool vw0 = (unsigned)w0 < (unsigned)W;
        const bool vw1 = (unsigned)w1 < (unsigned)W;
        wg[lvl * 4 + 0] = (vh0 && vw0) ? w00 : 0.f;
        wg[lvl * 4 + 1] = (vh0 && vw1) ? w01 : 0.f;
        wg[lvl * 4 + 2] = (vh1 && vw0) ? w10 : 0.f;
        wg[lvl * 4 + 3] = (vh1 && vw1) ? w11 : 0.f;

        const int h0c = min(max(h0, 0), H - 1);
        const int h1c = min(max(h1, 0), H - 1);
        const int w0c = min(max(w0, 0), W - 1);
        const int w1c = min(max(w1, 0), W - 1);

        const float* r0 = vb + (long)(S + h0c * W) * EMB;
        const float* r1 = vb + (long)(S + h1c * W) * EMB;

        d[lvl * 4 + 0] = *(const float4*)(r0 + (long)w0c * EMB);
        d[lvl * 4 + 1] = *(const float4*)(r0 + (long)w1c * EMB);
        d[lvl * 4 + 2] = *(const float4*)(r1 + (long)w0c * EMB);
        d[lvl * 4 + 3] = *(const float4*)(r1 + (long)w1c * EMB);
    }
}

__device__ __forceinline__ void consume_pair(const float4 d[16], const float wg[16],
                                             float4& acc)
{
    #pragma unroll
    for (int k = 0; k < 16; ++k) {
        acc.x = fmaf(d[k].x, wg[k], acc.x);
        acc.y = fmaf(d[k].y, wg[k], acc.y);
        acc.z = fmaf(d[k].z, wg[k], acc.z);
        acc.w = fmaf(d[k].w, wg[k], acc.w);
    }
}

__global__ __launch_bounds__(512)
void dfa_kernel(const float* __restrict__ value,
                const int*   __restrict__ shapes,   // (6,4,2) — cam0 rows used
                const int*   __restrict__ starts,   // (6,4)
                const float* __restrict__ loc,      // (B,A,P,6,2)
                const float* __restrict__ attw,     // (B,A,P,6,4,8)
                float*       __restrict__ out,      // (B,A,256)
                int A, int per_cam)
{
    const int tid  = threadIdx.x;
    const int wv   = tid >> 6;      // wave id 0..7
    const int lane = tid & 63;
    const int b = blockIdx.x / A;
    const int a = blockIdx.x - b * A;

    __shared__ int   sH[NLVL], sW[NLVL], sS[NLVL];
    __shared__ float red[NWAVES][EMB];
    if (tid < NLVL) {
        sH[tid] = shapes[tid * 2 + 0];
        sW[tid] = shapes[tid * 2 + 1];
        sS[tid] = starts[tid];
    }
    __syncthreads();

    int H_[NLVL], W_[NLVL], S_[NLVL];
    #pragma unroll
    for (int l = 0; l < NLVL; ++l) { H_[l] = sH[l]; W_[l] = sW[l]; S_[l] = sS[l]; }

    const int g = lane >> 3;        // group for channels 4*lane..4*lane+3
    const long ba = (long)b * A + a;
    const float* locp = loc  + ba * (NPTS * NCAMS * 2);
    const float* awp  = attw + ba * (NPTS * NCAMS * NLVL * NGROUPS) + g;

    float4 acc = make_float4(0.f, 0.f, 0.f, 0.f);
    float4 dA[16], dB[16];
    float  wA[16], wB[16];

    // 2-deep rotation: one pair's loads always in flight during the other's FMAs.
    int j = wv;
    issue_pair(j, value, locp, awp, b, per_cam, lane, H_, W_, S_, dA, wA);
    j += NWAVES;
    while (j + NWAVES < NPAIR) {
        issue_pair(j, value, locp, awp, b, per_cam, lane, H_, W_, S_, dB, wB);
        consume_pair(dA, wA, acc);
        issue_pair(j + NWAVES, value, locp, awp, b, per_cam, lane, H_, W_, S_, dA, wA);
        consume_pair(dB, wB, acc);
        j += 2 * NWAVES;
    }
    if (j < NPAIR) {
        issue_pair(j, value, locp, awp, b, per_cam, lane, H_, W_, S_, dB, wB);
        consume_pair(dA, wA, acc);
        consume_pair(dB, wB, acc);
    } else {
        consume_pair(dA, wA, acc);
    }

    *(float4*)&red[wv][lane * 4] = acc;
    __syncthreads();

    // fold 8 partial rows -> output using all 512 threads
    float s0 = 0.f;
    if (tid < 256) {
        s0 = red[0][tid] + red[1][tid] + red[2][tid] + red[3][tid];
    } else {
        const int t = tid - 256;
        red[4][t] = red[4][t] + red[5][t] + red[6][t] + red[7][t];
    }
    __syncthreads();
    if (tid < 256) {
        out[ba * EMB + tid] = s0 + red[4][tid];
    }
}

extern "C" void kernel_launch(void* const* d_in, const int* in_sizes, int n_in,
                              void* d_out, int out_size, void* d_ws, size_t ws_size,
                              hipStream_t stream) {
    const float* value  = (const float*)d_in[0];
    const int*   shapes = (const int*)d_in[1];
    const int*   starts = (const int*)d_in[2];
    const float* loc    = (const float*)d_in[3];
    const float* attw   = (const float*)d_in[4];
    float*       out    = (float*)d_out;

    const int B = 2;
    const int A = out_size / (EMB * B);                  // 900
    const int per_cam = in_sizes[0] / (B * EMB * NCAMS); // 14960

    dim3 grid(B * A);
    dim3 block(512);
    dfa_kernel<<<grid, block, 0, stream>>>(value, shapes, starts, loc, attw, out,
                                           A, per_cam);
}

// Round 10
// 416.004 us; speedup vs baseline: 1.1061x; 1.0697x over previous
//
#include <hip/hip_runtime.h>
#include <hip/hip_fp16.h>

constexpr int NCAMS   = 6;
constexpr int EMB     = 256;
constexpr int NGROUPS = 8;
constexpr int NLVL    = 4;
constexpr int NPTS    = 13;
constexpr int NPAIR   = NPTS * NCAMS;   // 78
constexpr int NWAVES  = 8;              // waves per block (512 threads)

// Settled facts (rounds 2-9):
//  - min-waves launch_bounds hints force VGPR=32 + GB-scale scratch spill.
//  - occupancy pins ~13 waves/CU for non-spilled shapes; more blocks/waves
//    and 2-deep MLP all leave L2-miss read BW at ~3.3-3.6 TB/s => that path
//    is a BW wall for this scattered pattern, not latency.
//  - epilogue kernels are ~free (constant ~190 us harness overhead).
// Round 10: halve the scattered bytes — stage value as fp16 in d_ws.

// ---------------- streaming f32 -> fp16 convert ----------------
__global__ __launch_bounds__(256)
void cvt_kernel(const float4* __restrict__ in, ushort4* __restrict__ out, int n4)
{
    for (int i = blockIdx.x * blockDim.x + threadIdx.x; i < n4;
         i += gridDim.x * blockDim.x) {
        const float4 v = in[i];
        ushort4 h;
        h.x = __half_as_ushort(__float2half_rn(v.x));
        h.y = __half_as_ushort(__float2half_rn(v.y));
        h.z = __half_as_ushort(__float2half_rn(v.z));
        h.w = __half_as_ushort(__float2half_rn(v.w));
        out[i] = h;
    }
}

// ---------------- fp16 sampling path ----------------
__device__ __forceinline__ void issue_pair_h(
    int pair,
    const __half* __restrict__ hval,
    const float* __restrict__ locp,
    const float* __restrict__ awp_g,
    int b, int per_cam, int lane,
    const int H_[NLVL], const int W_[NLVL], const int S_[NLVL],
    ushort4 d[16], float wg[16])
{
    const int p = pair / NCAMS;
    const int c = pair - p * NCAMS;
    const float lw = locp[pair * 2 + 0];
    const float lh = locp[pair * 2 + 1];
    const __half* vb = hval + ((long)(b * NCAMS + c) * per_cam) * EMB + lane * 4;
    const float* awpc = awp_g + pair * (NLVL * NGROUPS);

    #pragma unroll
    for (int lvl = 0; lvl < NLVL; ++lvl) {
        const int H = H_[lvl], W = W_[lvl], S = S_[lvl];
        const float hf = lh * (float)H - 0.5f;
        const float wf = lw * (float)W - 0.5f;
        const float h0f = floorf(hf), w0f = floorf(wf);
        const float dh = hf - h0f, dw = wf - w0f;
        const int h0 = (int)h0f, w0 = (int)w0f;
        const int h1 = h0 + 1,  w1 = w0 + 1;

        const float aw = awpc[lvl * NGROUPS];

        const float w00 = (1.f - dh) * (1.f - dw) * aw;
        const float w01 = (1.f - dh) * dw         * aw;
        const float w10 = dh         * (1.f - dw) * aw;
        const float w11 = dh         * dw         * aw;

        const bool vh0 = (unsigned)h0 < (unsigned)H;
        const bool vh1 = (unsigned)h1 < (unsigned)H;
        const bool vw0 = (unsigned)w0 < (unsigned)W;
        const bool vw1 = (unsigned)w1 < (unsigned)W;
        wg[lvl * 4 + 0] = (vh0 && vw0) ? w00 : 0.f;
        wg[lvl * 4 + 1] = (vh0 && vw1) ? w01 : 0.f;
        wg[lvl * 4 + 2] = (vh1 && vw0) ? w10 : 0.f;
        wg[lvl * 4 + 3] = (vh1 && vw1) ? w11 : 0.f;

        const int h0c = min(max(h0, 0), H - 1);
        const int h1c = min(max(h1, 0), H - 1);
        const int w0c = min(max(w0, 0), W - 1);
        const int w1c = min(max(w1, 0), W - 1);

        const __half* r0 = vb + (long)(S + h0c * W) * EMB;
        const __half* r1 = vb + (long)(S + h1c * W) * EMB;

        d[lvl * 4 + 0] = *(const ushort4*)(r0 + (long)w0c * EMB);
        d[lvl * 4 + 1] = *(const ushort4*)(r0 + (long)w1c * EMB);
        d[lvl * 4 + 2] = *(const ushort4*)(r1 + (long)w0c * EMB);
        d[lvl * 4 + 3] = *(const ushort4*)(r1 + (long)w1c * EMB);
    }
}

__device__ __forceinline__ void consume_pair_h(const ushort4 d[16], const float wg[16],
                                               float4& acc)
{
    #pragma unroll
    for (int k = 0; k < 16; ++k) {
        acc.x = fmaf(__half2float(__ushort_as_half(d[k].x)), wg[k], acc.x);
        acc.y = fmaf(__half2float(__ushort_as_half(d[k].y)), wg[k], acc.y);
        acc.z = fmaf(__half2float(__ushort_as_half(d[k].z)), wg[k], acc.z);
        acc.w = fmaf(__half2float(__ushort_as_half(d[k].w)), wg[k], acc.w);
    }
}

__global__ __launch_bounds__(512)
void dfa_kernel_h(const __half* __restrict__ hval,
                  const int*   __restrict__ shapes,
                  const int*   __restrict__ starts,
                  const float* __restrict__ loc,
                  const float* __restrict__ attw,
                  float*       __restrict__ out,
                  int A, int per_cam)
{
    const int tid  = threadIdx.x;
    const int wv   = tid >> 6;
    const int lane = tid & 63;
    const int b = blockIdx.x / A;
    const int a = blockIdx.x - b * A;

    __shared__ int   sH[NLVL], sW[NLVL], sS[NLVL];
    __shared__ float red[NWAVES][EMB];
    if (tid < NLVL) {
        sH[tid] = shapes[tid * 2 + 0];
        sW[tid] = shapes[tid * 2 + 1];
        sS[tid] = starts[tid];
    }
    __syncthreads();

    int H_[NLVL], W_[NLVL], S_[NLVL];
    #pragma unroll
    for (int l = 0; l < NLVL; ++l) { H_[l] = sH[l]; W_[l] = sW[l]; S_[l] = sS[l]; }

    const int g = lane >> 3;
    const long ba = (long)b * A + a;
    const float* locp = loc  + ba * (NPTS * NCAMS * 2);
    const float* awp  = attw + ba * (NPTS * NCAMS * NLVL * NGROUPS) + g;

    float4 acc = make_float4(0.f, 0.f, 0.f, 0.f);
    ushort4 dA[16], dB[16];
    float   wA[16], wB[16];

    int j = wv;
    issue_pair_h(j, hval, locp, awp, b, per_cam, lane, H_, W_, S_, dA, wA);
    j += NWAVES;
    while (j + NWAVES < NPAIR) {
        issue_pair_h(j, hval, locp, awp, b, per_cam, lane, H_, W_, S_, dB, wB);
        consume_pair_h(dA, wA, acc);
        issue_pair_h(j + NWAVES, hval, locp, awp, b, per_cam, lane, H_, W_, S_, dA, wA);
        consume_pair_h(dB, wB, acc);
        j += 2 * NWAVES;
    }
    if (j < NPAIR) {
        issue_pair_h(j, hval, locp, awp, b, per_cam, lane, H_, W_, S_, dB, wB);
        consume_pair_h(dA, wA, acc);
        consume_pair_h(dB, wB, acc);
    } else {
        consume_pair_h(dA, wA, acc);
    }

    *(float4*)&red[wv][lane * 4] = acc;
    __syncthreads();

    float s0 = 0.f;
    if (tid < 256) {
        s0 = red[0][tid] + red[1][tid] + red[2][tid] + red[3][tid];
    } else {
        const int t = tid - 256;
        red[4][t] = red[4][t] + red[5][t] + red[6][t] + red[7][t];
    }
    __syncthreads();
    if (tid < 256) {
        out[ba * EMB + tid] = s0 + red[4][tid];
    }
}

// ---------------- f32 fallback (round-9 kernel) ----------------
__device__ __forceinline__ void issue_pair_f(
    int pair,
    const float* __restrict__ value,
    const float* __restrict__ locp,
    const float* __restrict__ awp_g,
    int b, int per_cam, int lane,
    const int H_[NLVL], const int W_[NLVL], const int S_[NLVL],
    float4 d[16], float wg[16])
{
    const int p = pair / NCAMS;
    const int c = pair - p * NCAMS;
    const float lw = locp[pair * 2 + 0];
    const float lh = locp[pair * 2 + 1];
    const float* vb = value + ((long)(b * NCAMS + c) * per_cam) * EMB + lane * 4;
    const float* awpc = awp_g + pair * (NLVL * NGROUPS);

    #pragma unroll
    for (int lvl = 0; lvl < NLVL; ++lvl) {
        const int H = H_[lvl], W = W_[lvl], S = S_[lvl];
        const float hf = lh * (float)H - 0.5f;
        const float wf = lw * (float)W - 0.5f;
        const float h0f = floorf(hf), w0f = floorf(wf);
        const float dh = hf - h0f, dw = wf - w0f;
        const int h0 = (int)h0f, w0 = (int)w0f;
        const int h1 = h0 + 1,  w1 = w0 + 1;
        const float aw = awpc[lvl * NGROUPS];
        const float w00 = (1.f - dh) * (1.f - dw) * aw;
        const float w01 = (1.f - dh) * dw         * aw;
        const float w10 = dh         * (1.f - dw) * aw;
        const float w11 = dh         * dw         * aw;
        const bool vh0 = (unsigned)h0 < (unsigned)H;
        const bool vh1 = (unsigned)h1 < (unsigned)H;
        const bool vw0 = (unsigned)w0 < (unsigned)W;
        const bool vw1 = (unsigned)w1 < (unsigned)W;
        wg[lvl * 4 + 0] = (vh0 && vw0) ? w00 : 0.f;
        wg[lvl * 4 + 1] = (vh0 && vw1) ? w01 : 0.f;
        wg[lvl * 4 + 2] = (vh1 && vw0) ? w10 : 0.f;
        wg[lvl * 4 + 3] = (vh1 && vw1) ? w11 : 0.f;
        const int h0c = min(max(h0, 0), H - 1);
        const int h1c = min(max(h1, 0), H - 1);
        const int w0c = min(max(w0, 0), W - 1);
        const int w1c = min(max(w1, 0), W - 1);
        const float* r0 = vb + (long)(S + h0c * W) * EMB;
        const float* r1 = vb + (long)(S + h1c * W) * EMB;
        d[lvl * 4 + 0] = *(const float4*)(r0 + (long)w0c * EMB);
        d[lvl * 4 + 1] = *(const float4*)(r0 + (long)w1c * EMB);
        d[lvl * 4 + 2] = *(const float4*)(r1 + (long)w0c * EMB);
        d[lvl * 4 + 3] = *(const float4*)(r1 + (long)w1c * EMB);
    }
}

__device__ __forceinline__ void consume_pair_f(const float4 d[16], const float wg[16],
                                               float4& acc)
{
    #pragma unroll
    for (int k = 0; k < 16; ++k) {
        acc.x = fmaf(d[k].x, wg[k], acc.x);
        acc.y = fmaf(d[k].y, wg[k], acc.y);
        acc.z = fmaf(d[k].z, wg[k], acc.z);
        acc.w = fmaf(d[k].w, wg[k], acc.w);
    }
}

__global__ __launch_bounds__(512)
void dfa_kernel_f(const float* __restrict__ value,
                  const int*   __restrict__ shapes,
                  const int*   __restrict__ starts,
                  const float* __restrict__ loc,
                  const float* __restrict__ attw,
                  float*       __restrict__ out,
                  int A, int per_cam)
{
    const int tid  = threadIdx.x;
    const int wv   = tid >> 6;
    const int lane = tid & 63;
    const int b = blockIdx.x / A;
    const int a = blockIdx.x - b * A;

    __shared__ int   sH[NLVL], sW[NLVL], sS[NLVL];
    __shared__ float red[NWAVES][EMB];
    if (tid < NLVL) {
        sH[tid] = shapes[tid * 2 + 0];
        sW[tid] = shapes[tid * 2 + 1];
        sS[tid] = starts[tid];
    }
    __syncthreads();

    int H_[NLVL], W_[NLVL], S_[NLVL];
    #pragma unroll
    for (int l = 0; l < NLVL; ++l) { H_[l] = sH[l]; W_[l] = sW[l]; S_[l] = sS[l]; }

    const int g = lane >> 3;
    const long ba = (long)b * A + a;
    const float* locp = loc  + ba * (NPTS * NCAMS * 2);
    const float* awp  = attw + ba * (NPTS * NCAMS * NLVL * NGROUPS) + g;

    float4 acc = make_float4(0.f, 0.f, 0.f, 0.f);
    float4 dA[16], dB[16];
    float  wA[16], wB[16];

    int j = wv;
    issue_pair_f(j, value, locp, awp, b, per_cam, lane, H_, W_, S_, dA, wA);
    j += NWAVES;
    while (j + NWAVES < NPAIR) {
        issue_pair_f(j, value, locp, awp, b, per_cam, lane, H_, W_, S_, dB, wB);
        consume_pair_f(dA, wA, acc);
        issue_pair_f(j + NWAVES, value, locp, awp, b, per_cam, lane, H_, W_, S_, dA, wA);
        consume_pair_f(dB, wB, acc);
        j += 2 * NWAVES;
    }
    if (j < NPAIR) {
        issue_pair_f(j, value, locp, awp, b, per_cam, lane, H_, W_, S_, dB, wB);
        consume_pair_f(dA, wA, acc);
        consume_pair_f(dB, wB, acc);
    } else {
        consume_pair_f(dA, wA, acc);
    }

    *(float4*)&red[wv][lane * 4] = acc;
    __syncthreads();

    float s0 = 0.f;
    if (tid < 256) {
        s0 = red[0][tid] + red[1][tid] + red[2][tid] + red[3][tid];
    } else {
        const int t = tid - 256;
        red[4][t] = red[4][t] + red[5][t] + red[6][t] + red[7][t];
    }
    __syncthreads();
    if (tid < 256) {
        out[ba * EMB + tid] = s0 + red[4][tid];
    }
}

extern "C" void kernel_launch(void* const* d_in, const int* in_sizes, int n_in,
                              void* d_out, int out_size, void* d_ws, size_t ws_size,
                              hipStream_t stream) {
    const float* value  = (const float*)d_in[0];
    const int*   shapes = (const int*)d_in[1];
    const int*   starts = (const int*)d_in[2];
    const float* loc    = (const float*)d_in[3];
    const float* attw   = (const float*)d_in[4];
    float*       out    = (float*)d_out;

    const int B = 2;
    const int A = out_size / (EMB * B);                  // 900
    const int per_cam = in_sizes[0] / (B * EMB * NCAMS); // 14960

    dim3 grid(B * A);
    dim3 block(512);

    const size_t need = (size_t)in_sizes[0] * sizeof(__half);  // ~92 MB
    if (ws_size >= need) {
        __half* hval = (__half*)d_ws;
        const int n4 = in_sizes[0] / 4;
        cvt_kernel<<<2048, 256, 0, stream>>>((const float4*)value, (ushort4*)hval, n4);
        dfa_kernel_h<<<grid, block, 0, stream>>>(hval, shapes, starts, loc, attw,
                                                 out, A, per_cam);
    } else {
        dfa_kernel_f<<<grid, block, 0, stream>>>(value, shapes, starts, loc, attw,
                                                 out, A, per_cam);
    }
}

// Round 12
// 395.680 us; speedup vs baseline: 1.1629x; 1.0514x over previous
//
#include <hip/hip_runtime.h>
#include <hip/hip_fp16.h>

constexpr int NCAMS   = 6;
constexpr int EMB     = 256;
constexpr int NGROUPS = 8;
constexpr int NLVL    = 4;
constexpr int NPTS    = 13;
constexpr int NPAIR   = NPTS * NCAMS;   // 78
constexpr int NWAVES  = 8;              // waves per block (512 threads)

// Settled facts (rounds 2-10):
//  - min-waves launch_bounds hints force VGPR=32 + GB-scale scratch spill.
//  - occupancy counter pins ~13 waves/CU for non-spilled shapes regardless of
//    packaging; concurrency knobs don't move the needle.
//  - f32 path saturates ~3.4-3.6 TB/s on the L2-miss path (byte wall);
//    fp16 at 8 B/lane/request dropped to 2.25 TB/s => request-rate limited.
//  - harness overhead ~190 us constant; cvt ~45 us.
// Round 11/12: 16 B/lane wave-loads — one load covers BOTH w-columns of a row
// (lanes 0-31 -> w0, lanes 32-63 -> w1). 2 loads per (pair,level) not 4.

// ---------------- streaming f32 -> fp16 convert ----------------
__global__ __launch_bounds__(256)
void cvt_kernel(const float4* __restrict__ in, ushort4* __restrict__ out, int n4)
{
    for (int i = blockIdx.x * blockDim.x + threadIdx.x; i < n4;
         i += gridDim.x * blockDim.x) {
        const float4 v = in[i];
        ushort4 h;
        h.x = __half_as_ushort(__float2half_rn(v.x));
        h.y = __half_as_ushort(__float2half_rn(v.y));
        h.z = __half_as_ushort(__float2half_rn(v.z));
        h.w = __half_as_ushort(__float2half_rn(v.w));
        out[i] = h;
    }
}

// ---------------- fp16 sampling path (paired-column loads) ----------------
// Each lane: half_id = lane&31, side = lane>>5 (0 -> w0 column, 1 -> w1).
// Lane loads 8 channels [8*half_id .. 8*half_id+8) (16 B) of its side's
// column, rows h0 and h1, for each level: 2 uint4 loads per (pair,level).
__device__ __forceinline__ void issue_pair_h(
    int pair,
    const __half* __restrict__ hval,
    const float* __restrict__ locp,
    const float* __restrict__ awp_g,
    int b, int per_cam, int half_id, int side,
    const int H_[NLVL], const int W_[NLVL], const int S_[NLVL],
    uint4 d[8], float wg[8])
{
    const int c = pair % NCAMS;
    const float lw = locp[pair * 2 + 0];
    const float lh = locp[pair * 2 + 1];
    const __half* vb = hval + ((long)(b * NCAMS + c) * per_cam) * EMB + half_id * 8;
    const float* awpc = awp_g + pair * (NLVL * NGROUPS);

    #pragma unroll
    for (int lvl = 0; lvl < NLVL; ++lvl) {
        const int H = H_[lvl], W = W_[lvl], S = S_[lvl];
        const float hf = lh * (float)H - 0.5f;
        const float wf = lw * (float)W - 0.5f;
        const float h0f = floorf(hf), w0f = floorf(wf);
        const float dh = hf - h0f, dw = wf - w0f;
        const int h0 = (int)h0f, w0 = (int)w0f;
        const int h1 = h0 + 1;
        const int wS = w0 + side;          // this lane's column

        const float aw = awpc[lvl * NGROUPS];
        const float cw = side ? dw : (1.f - dw);

        const bool vw  = (unsigned)wS < (unsigned)W;
        const bool vh0 = (unsigned)h0 < (unsigned)H;
        const bool vh1 = (unsigned)h1 < (unsigned)H;
        float wt = (1.f - dh) * cw * aw;   // top row (h0) weight
        float wb = dh         * cw * aw;   // bottom row (h1) weight
        wt = (vh0 && vw) ? wt : 0.f;
        wb = (vh1 && vw) ? wb : 0.f;

        const int wc  = min(max(wS, 0), W - 1);
        const int h0c = min(max(h0, 0), H - 1);
        const int h1c = min(max(h1, 0), H - 1);

        d[lvl * 2 + 0] = *(const uint4*)(vb + (long)(S + h0c * W + wc) * EMB);
        d[lvl * 2 + 1] = *(const uint4*)(vb + (long)(S + h1c * W + wc) * EMB);
        wg[lvl * 2 + 0] = wt;
        wg[lvl * 2 + 1] = wb;
    }
}

__device__ __forceinline__ void consume_pair_h(const uint4 d[8], const float wg[8],
                                               float acc[8])
{
    #pragma unroll
    for (int k = 0; k < 8; ++k) {
        const float w = wg[k];
        const uint4 v = d[k];
        const __half2* h2 = reinterpret_cast<const __half2*>(&v);
        #pragma unroll
        for (int q = 0; q < 4; ++q) {
            const float2 f = __half22float2(h2[q]);
            acc[2 * q + 0] = fmaf(f.x, w, acc[2 * q + 0]);
            acc[2 * q + 1] = fmaf(f.y, w, acc[2 * q + 1]);
        }
    }
}

__global__ __launch_bounds__(512)
void dfa_kernel_h(const __half* __restrict__ hval,
                  const int*   __restrict__ shapes,
                  const int*   __restrict__ starts,
                  const float* __restrict__ loc,
                  const float* __restrict__ attw,
                  float*       __restrict__ out,
                  int A, int per_cam)
{
    const int tid  = threadIdx.x;
    const int wv   = tid >> 6;
    const int lane = tid & 63;
    const int b = blockIdx.x / A;
    const int a = blockIdx.x - b * A;

    __shared__ int   sH[NLVL], sW[NLVL], sS[NLVL];
    __shared__ float red[NWAVES][EMB];
    if (tid < NLVL) {
        sH[tid] = shapes[tid * 2 + 0];
        sW[tid] = shapes[tid * 2 + 1];
        sS[tid] = starts[tid];
    }
    __syncthreads();

    int H_[NLVL], W_[NLVL], S_[NLVL];
    #pragma unroll
    for (int l = 0; l < NLVL; ++l) { H_[l] = sH[l]; W_[l] = sW[l]; S_[l] = sS[l]; }

    const int half_id = lane & 31;
    const int side    = lane >> 5;       // 0: w0 column, 1: w1 column
    const int g       = half_id >> 2;    // group of channels [8*half_id ..)

    const long ba = (long)b * A + a;
    const float* locp = loc  + ba * (NPTS * NCAMS * 2);
    const float* awp  = attw + ba * (NPTS * NCAMS * NLVL * NGROUPS) + g;

    float acc[8];
    #pragma unroll
    for (int j = 0; j < 8; ++j) acc[j] = 0.f;
    uint4 dA[8], dB[8];
    float wA[8], wB[8];

    int j = wv;
    issue_pair_h(j, hval, locp, awp, b, per_cam, half_id, side, H_, W_, S_, dA, wA);
    j += NWAVES;
    while (j + NWAVES < NPAIR) {
        issue_pair_h(j, hval, locp, awp, b, per_cam, half_id, side, H_, W_, S_, dB, wB);
        consume_pair_h(dA, wA, acc);
        issue_pair_h(j + NWAVES, hval, locp, awp, b, per_cam, half_id, side, H_, W_, S_, dA, wA);
        consume_pair_h(dB, wB, acc);
        j += 2 * NWAVES;
    }
    if (j < NPAIR) {
        issue_pair_h(j, hval, locp, awp, b, per_cam, half_id, side, H_, W_, S_, dB, wB);
        consume_pair_h(dA, wA, acc);
        consume_pair_h(dB, wB, acc);
    } else {
        consume_pair_h(dA, wA, acc);
    }

    // merge w0/w1 column partials: lane i (<32) += lane i+32
    #pragma unroll
    for (int k = 0; k < 8; ++k) acc[k] += __shfl_down(acc[k], 32);

    if (lane < 32) {
        float* r = &red[wv][half_id * 8];
        *(float4*)(r + 0) = make_float4(acc[0], acc[1], acc[2], acc[3]);
        *(float4*)(r + 4) = make_float4(acc[4], acc[5], acc[6], acc[7]);
    }
    __syncthreads();

    float s0 = 0.f;
    if (tid < 256) {
        s0 = red[0][tid] + red[1][tid] + red[2][tid] + red[3][tid];
    } else {
        const int t = tid - 256;
        red[4][t] = red[4][t] + red[5][t] + red[6][t] + red[7][t];
    }
    __syncthreads();
    if (tid < 256) {
        out[ba * EMB + tid] = s0 + red[4][tid];
    }
}

// ---------------- f32 fallback (round-9 kernel, ws too small) ----------------
__device__ __forceinline__ void issue_pair_f(
    int pair,
    const float* __restrict__ value,
    const float* __restrict__ locp,
    const float* __restrict__ awp_g,
    int b, int per_cam, int lane,
    const int H_[NLVL], const int W_[NLVL], const int S_[NLVL],
    float4 d[16], float wg[16])
{
    const int p = pair / NCAMS;
    const int c = pair - p * NCAMS;
    const float lw = locp[pair * 2 + 0];
    const float lh = locp[pair * 2 + 1];
    const float* vb = value + ((long)(b * NCAMS + c) * per_cam) * EMB + lane * 4;
    const float* awpc = awp_g + pair * (NLVL * NGROUPS);

    #pragma unroll
    for (int lvl = 0; lvl < NLVL; ++lvl) {
        const int H = H_[lvl], W = W_[lvl], S = S_[lvl];
        const float hf = lh * (float)H - 0.5f;
        const float wf = lw * (float)W - 0.5f;
        const float h0f = floorf(hf), w0f = floorf(wf);
        const float dh = hf - h0f, dw = wf - w0f;
        const int h0 = (int)h0f, w0 = (int)w0f;
        const int h1 = h0 + 1,  w1 = w0 + 1;
        const float aw = awpc[lvl * NGROUPS];
        const float w00 = (1.f - dh) * (1.f - dw) * aw;
        const float w01 = (1.f - dh) * dw         * aw;
        const float w10 = dh         * (1.f - dw) * aw;
        const float w11 = dh         * dw         * aw;
        const bool vh0 = (unsigned)h0 < (unsigned)H;
        const bool vh1 = (unsigned)h1 < (unsigned)H;
        const bool vw0 = (unsigned)w0 < (unsigned)W;
        const bool vw1 = (unsigned)w1 < (unsigned)W;
        wg[lvl * 4 + 0] = (vh0 && vw0) ? w00 : 0.f;
        wg[lvl * 4 + 1] = (vh0 && vw1) ? w01 : 0.f;
        wg[lvl * 4 + 2] = (vh1 && vw0) ? w10 : 0.f;
        wg[lvl * 4 + 3] = (vh1 && vw1) ? w11 : 0.f;
        const int h0c = min(max(h0, 0), H - 1);
        const int h1c = min(max(h1, 0), H - 1);
        const int w0c = min(max(w0, 0), W - 1);
        const int w1c = min(max(w1, 0), W - 1);
        const float* r0 = vb + (long)(S + h0c * W) * EMB;
        const float* r1 = vb + (long)(S + h1c * W) * EMB;
        d[lvl * 4 + 0] = *(const float4*)(r0 + (long)w0c * EMB);
        d[lvl * 4 + 1] = *(const float4*)(r0 + (long)w1c * EMB);
        d[lvl * 4 + 2] = *(const float4*)(r1 + (long)w0c * EMB);
        d[lvl * 4 + 3] = *(const float4*)(r1 + (long)w1c * EMB);
    }
}

__device__ __forceinline__ void consume_pair_f(const float4 d[16], const float wg[16],
                                               float4& acc)
{
    #pragma unroll
    for (int k = 0; k < 16; ++k) {
        acc.x = fmaf(d[k].x, wg[k], acc.x);
        acc.y = fmaf(d[k].y, wg[k], acc.y);
        acc.z = fmaf(d[k].z, wg[k], acc.z);
        acc.w = fmaf(d[k].w, wg[k], acc.w);
    }
}

__global__ __launch_bounds__(512)
void dfa_kernel_f(const float* __restrict__ value,
                  const int*   __restrict__ shapes,
                  const int*   __restrict__ starts,
                  const float* __restrict__ loc,
                  const float* __restrict__ attw,
                  float*       __restrict__ out,
                  int A, int per_cam)
{
    const int tid  = threadIdx.x;
    const int wv   = tid >> 6;
    const int lane = tid & 63;
    const int b = blockIdx.x / A;
    const int a = blockIdx.x - b * A;

    __shared__ int   sH[NLVL], sW[NLVL], sS[NLVL];
    __shared__ float red[NWAVES][EMB];
    if (tid < NLVL) {
        sH[tid] = shapes[tid * 2 + 0];
        sW[tid] = shapes[tid * 2 + 1];
        sS[tid] = starts[tid];
    }
    __syncthreads();

    int H_[NLVL], W_[NLVL], S_[NLVL];
    #pragma unroll
    for (int l = 0; l < NLVL; ++l) { H_[l] = sH[l]; W_[l] = sW[l]; S_[l] = sS[l]; }

    const int g = lane >> 3;
    const long ba = (long)b * A + a;
    const float* locp = loc  + ba * (NPTS * NCAMS * 2);
    const float* awp  = attw + ba * (NPTS * NCAMS * NLVL * NGROUPS) + g;

    float4 acc = make_float4(0.f, 0.f, 0.f, 0.f);
    float4 dA[16], dB[16];
    float  wA[16], wB[16];

    int j = wv;
    issue_pair_f(j, value, locp, awp, b, per_cam, lane, H_, W_, S_, dA, wA);
    j += NWAVES;
    while (j + NWAVES < NPAIR) {
        issue_pair_f(j, value, locp, awp, b, per_cam, lane, H_, W_, S_, dB, wB);
        consume_pair_f(dA, wA, acc);
        issue_pair_f(j + NWAVES, value, locp, awp, b, per_cam, lane, H_, W_, S_, dA, wA);
        consume_pair_f(dB, wB, acc);
        j += 2 * NWAVES;
    }
    if (j < NPAIR) {
        issue_pair_f(j, value, locp, awp, b, per_cam, lane, H_, W_, S_, dB, wB);
        consume_pair_f(dA, wA, acc);
        consume_pair_f(dB, wB, acc);
    } else {
        consume_pair_f(dA, wA, acc);
    }

    *(float4*)&red[wv][lane * 4] = acc;
    __syncthreads();

    float s0 = 0.f;
    if (tid < 256) {
        s0 = red[0][tid] + red[1][tid] + red[2][tid] + red[3][tid];
    } else {
        const int t = tid - 256;
        red[4][t] = red[4][t] + red[5][t] + red[6][t] + red[7][t];
    }
    __syncthreads();
    if (tid < 256) {
        out[ba * EMB + tid] = s0 + red[4][tid];
    }
}

extern "C" void kernel_launch(void* const* d_in, const int* in_sizes, int n_in,
                              void* d_out, int out_size, void* d_ws, size_t ws_size,
                              hipStream_t stream) {
    const float* value  = (const float*)d_in[0];
    const int*   shapes = (const int*)d_in[1];
    const int*   starts = (const int*)d_in[2];
    const float* loc    = (const float*)d_in[3];
    const float* attw   = (const float*)d_in[4];
    float*       out    = (float*)d_out;

    const int B = 2;
    const int A = out_size / (EMB * B);                  // 900
    const int per_cam = in_sizes[0] / (B * EMB * NCAMS); // 14960

    dim3 grid(B * A);
    dim3 block(512);

    const size_t need = (size_t)in_sizes[0] * sizeof(__half);  // ~92 MB
    if (ws_size >= need) {
        __half* hval = (__half*)d_ws;
        const int n4 = in_sizes[0] / 4;
        cvt_kernel<<<2048, 256, 0, stream>>>((const float4*)value, (ushort4*)hval, n4);
        dfa_kernel_h<<<grid, block, 0, stream>>>(hval, shapes, starts, loc, attw,
                                                 out, A, per_cam);
    } else {
        dfa_kernel_f<<<grid, block, 0, stream>>>(value, shapes, starts, loc, attw,
                                                 out, A, per_cam);
    }
}

// Round 14
// 378.261 us; speedup vs baseline: 1.2164x; 1.0460x over previous
//
#include <hip/hip_runtime.h>
#include <hip/hip_fp16.h>

constexpr int NCAMS   = 6;
constexpr int EMB     = 256;
constexpr int NGROUPS = 8;
constexpr int NLVL    = 4;
constexpr int NPTS    = 13;
constexpr int NPAIR   = NPTS * NCAMS;   // 78
constexpr int NWAVES  = 8;              // waves per block (512 threads)
constexpr int NGEOM   = NPAIR * NLVL * 2;        // 624 (pair,lvl,side)
constexpr int NAW     = NPAIR * NLVL * NGROUPS;  // 2496

// Settled facts (rounds 2-12):
//  - min-waves launch_bounds hints force VGPR=32 + GB-scale scratch spill.
//  - occupancy pins low for non-spilled shapes; concurrency knobs don't help.
//  - f32 byte wall ~3.5 TB/s on scattered L2-miss path; fp16 @ 8 B/lane was
//    request-rate bound (2.25 TB/s); 16 B/lane paired-column loads fixed it
//    (127 us, 2.9 TB/s, VALUBusy 49%).
// Round 13/14: kill redundant VALU. Geometry precomputed once per block into
// LDS (was recomputed by all 8 waves), attn weights staged into LDS
// (removes 4 scattered reads/pair), consume via packed __hfma2.

// ---------------- streaming f32 -> fp16 convert ----------------
__global__ __launch_bounds__(256)
void cvt_kernel(const float4* __restrict__ in, ushort4* __restrict__ out, int n4)
{
    for (int i = blockIdx.x * blockDim.x + threadIdx.x; i < n4;
         i += gridDim.x * blockDim.x) {
        const float4 v = in[i];
        ushort4 h;
        h.x = __half_as_ushort(__float2half_rn(v.x));
        h.y = __half_as_ushort(__float2half_rn(v.y));
        h.z = __half_as_ushort(__float2half_rn(v.z));
        h.w = __half_as_ushort(__float2half_rn(v.w));
        out[i] = h;
    }
}

// ---------------- fp16 sampling path ----------------
__global__ __launch_bounds__(512)
void dfa_kernel_h(const __half* __restrict__ hval,
                  const int*   __restrict__ shapes,
                  const int*   __restrict__ starts,
                  const float* __restrict__ loc,
                  const float* __restrict__ attw,
                  float*       __restrict__ out,
                  int A, int per_cam)
{
    const int tid  = threadIdx.x;
    const int wv   = tid >> 6;
    const int lane = tid & 63;
    const int b = blockIdx.x / A;
    const int a = blockIdx.x - b * A;

    __shared__ float attw_s[NAW];        // 9984 B
    __shared__ int   gOffT[NGEOM];       // 2496 B  (element offset of top row)
    __shared__ int   gOffB[NGEOM];       // 2496 B  (bottom row)
    __shared__ float gWT[NGEOM];         // 2496 B  (geom weight top, excl attn)
    __shared__ float gWB[NGEOM];         // 2496 B
    __shared__ float red[NWAVES][EMB];   // 8192 B

    const long ba = (long)b * A + a;
    const float* locp = loc  + ba * (NPTS * NCAMS * 2);
    const float* awp  = attw + ba * (long)NAW;

    // ---- setup phase 1: stage attention weights (coalesced) ----
    for (int i = tid; i < NAW; i += 512) attw_s[i] = awp[i];

    // ---- setup phase 2: geometry for all (pair,lvl,side) ----
    for (int item = tid; item < NGEOM; item += 512) {
        const int side = item & 1;
        const int t    = item >> 1;       // 0..311
        const int lvl  = t & 3;
        const int pair = t >> 2;

        const int H = shapes[lvl * 2 + 0];
        const int W = shapes[lvl * 2 + 1];
        const int S = starts[lvl];

        const float lw = locp[pair * 2 + 0];
        const float lh = locp[pair * 2 + 1];

        const float hf = lh * (float)H - 0.5f;
        const float wf = lw * (float)W - 0.5f;
        const float h0f = floorf(hf), w0f = floorf(wf);
        const float dh = hf - h0f, dw = wf - w0f;
        const int h0 = (int)h0f, w0 = (int)w0f;
        const int h1 = h0 + 1;
        const int wS = w0 + side;

        const float cw = side ? dw : (1.f - dw);
        const bool vw  = (unsigned)wS < (unsigned)W;
        const bool vh0 = (unsigned)h0 < (unsigned)H;
        const bool vh1 = (unsigned)h1 < (unsigned)H;

        gWT[item] = (vh0 && vw) ? (1.f - dh) * cw : 0.f;
        gWB[item] = (vh1 && vw) ? dh * cw         : 0.f;

        const int wc  = min(max(wS, 0), W - 1);
        const int h0c = min(max(h0, 0), H - 1);
        const int h1c = min(max(h1, 0), H - 1);
        gOffT[item] = (S + h0c * W + wc) * EMB;
        gOffB[item] = (S + h1c * W + wc) * EMB;
    }
    __syncthreads();

    // ---- main loop ----
    const int half_id = lane & 31;
    const int side    = lane >> 5;       // 0 -> w0 column, 1 -> w1
    const int g       = half_id >> 2;

    __half2 acc2[4];
    #pragma unroll
    for (int q = 0; q < 4; ++q) acc2[q] = __float2half2_rn(0.f);

    uint4 dA[8], dB[8];
    __half2 wA[8], wB[8];

    // issue: read geometry from LDS, fire 8 global loads for one pair
    auto issue = [&](int pair, uint4 d[8], __half2 wg[8]) {
        const int c = pair % NCAMS;
        const __half* base = hval + ((long)(b * NCAMS + c) * per_cam) * EMB
                                  + half_id * 8;
        const int gbase = pair * (NLVL * 2) + side;
        const int abase = pair * (NLVL * NGROUPS) + g;
        #pragma unroll
        for (int lvl = 0; lvl < NLVL; ++lvl) {
            const int idx = gbase + lvl * 2;
            const float aw = attw_s[abase + lvl * NGROUPS];
            wg[lvl * 2 + 0] = __float2half2_rn(gWT[idx] * aw);
            wg[lvl * 2 + 1] = __float2half2_rn(gWB[idx] * aw);
            d[lvl * 2 + 0] = *(const uint4*)(base + gOffT[idx]);
            d[lvl * 2 + 1] = *(const uint4*)(base + gOffB[idx]);
        }
    };
    auto consume = [&](const uint4 d[8], const __half2 wg[8]) {
        #pragma unroll
        for (int k = 0; k < 8; ++k) {
            const __half2* h2 = reinterpret_cast<const __half2*>(&d[k]);
            #pragma unroll
            for (int q = 0; q < 4; ++q)
                acc2[q] = __hfma2(h2[q], wg[k], acc2[q]);
        }
    };

    int j = wv;
    issue(j, dA, wA);
    j += NWAVES;
    while (j + NWAVES < NPAIR) {
        issue(j, dB, wB);
        consume(dA, wA);
        issue(j + NWAVES, dA, wA);
        consume(dB, wB);
        j += 2 * NWAVES;
    }
    if (j < NPAIR) {
        issue(j, dB, wB);
        consume(dA, wA);
        consume(dB, wB);
    } else {
        consume(dA, wA);
    }

    // fp16 partial -> f32, merge w0/w1 sides (lane i += lane i+32)
    float af[8];
    #pragma unroll
    for (int q = 0; q < 4; ++q) {
        const float2 f = __half22float2(acc2[q]);
        af[2 * q + 0] = f.x;
        af[2 * q + 1] = f.y;
    }
    #pragma unroll
    for (int k = 0; k < 8; ++k) af[k] += __shfl_down(af[k], 32);

    if (lane < 32) {
        float* r = &red[wv][half_id * 8];
        *(float4*)(r + 0) = make_float4(af[0], af[1], af[2], af[3]);
        *(float4*)(r + 4) = make_float4(af[4], af[5], af[6], af[7]);
    }
    __syncthreads();

    float s0 = 0.f;
    if (tid < 256) {
        s0 = red[0][tid] + red[1][tid] + red[2][tid] + red[3][tid];
    } else {
        const int t = tid - 256;
        red[4][t] = red[4][t] + red[5][t] + red[6][t] + red[7][t];
    }
    __syncthreads();
    if (tid < 256) {
        out[ba * EMB + tid] = s0 + red[4][tid];
    }
}

// ---------------- f32 fallback (round-9 kernel, ws too small) ----------------
__device__ __forceinline__ void issue_pair_f(
    int pair,
    const float* __restrict__ value,
    const float* __restrict__ locp,
    const float* __restrict__ awp_g,
    int b, int per_cam, int lane,
    const int H_[NLVL], const int W_[NLVL], const int S_[NLVL],
    float4 d[16], float wg[16])
{
    const int p = pair / NCAMS;
    const int c = pair - p * NCAMS;
    const float lw = locp[pair * 2 + 0];
    const float lh = locp[pair * 2 + 1];
    const float* vb = value + ((long)(b * NCAMS + c) * per_cam) * EMB + lane * 4;
    const float* awpc = awp_g + pair * (NLVL * NGROUPS);

    #pragma unroll
    for (int lvl = 0; lvl < NLVL; ++lvl) {
        const int H = H_[lvl], W = W_[lvl], S = S_[lvl];
        const float hf = lh * (float)H - 0.5f;
        const float wf = lw * (float)W - 0.5f;
        const float h0f = floorf(hf), w0f = floorf(wf);
        const float dh = hf - h0f, dw = wf - w0f;
        const int h0 = (int)h0f, w0 = (int)w0f;
        const int h1 = h0 + 1,  w1 = w0 + 1;
        const float aw = awpc[lvl * NGROUPS];
        const float w00 = (1.f - dh) * (1.f - dw) * aw;
        const float w01 = (1.f - dh) * dw         * aw;
        const float w10 = dh         * (1.f - dw) * aw;
        const float w11 = dh         * dw         * aw;
        const bool vh0 = (unsigned)h0 < (unsigned)H;
        const bool vh1 = (unsigned)h1 < (unsigned)H;
        const bool vw0 = (unsigned)w0 < (unsigned)W;
        const bool vw1 = (unsigned)w1 < (unsigned)W;
        wg[lvl * 4 + 0] = (vh0 && vw0) ? w00 : 0.f;
        wg[lvl * 4 + 1] = (vh0 && vw1) ? w01 : 0.f;
        wg[lvl * 4 + 2] = (vh1 && vw0) ? w10 : 0.f;
        wg[lvl * 4 + 3] = (vh1 && vw1) ? w11 : 0.f;
        const int h0c = min(max(h0, 0), H - 1);
        const int h1c = min(max(h1, 0), H - 1);
        const int w0c = min(max(w0, 0), W - 1);
        const int w1c = min(max(w1, 0), W - 1);
        const float* r0 = vb + (long)(S + h0c * W) * EMB;
        const float* r1 = vb + (long)(S + h1c * W) * EMB;
        d[lvl * 4 + 0] = *(const float4*)(r0 + (long)w0c * EMB);
        d[lvl * 4 + 1] = *(const float4*)(r0 + (long)w1c * EMB);
        d[lvl * 4 + 2] = *(const float4*)(r1 + (long)w0c * EMB);
        d[lvl * 4 + 3] = *(const float4*)(r1 + (long)w1c * EMB);
    }
}

__device__ __forceinline__ void consume_pair_f(const float4 d[16], const float wg[16],
                                               float4& acc)
{
    #pragma unroll
    for (int k = 0; k < 16; ++k) {
        acc.x = fmaf(d[k].x, wg[k], acc.x);
        acc.y = fmaf(d[k].y, wg[k], acc.y);
        acc.z = fmaf(d[k].z, wg[k], acc.z);
        acc.w = fmaf(d[k].w, wg[k], acc.w);
    }
}

__global__ __launch_bounds__(512)
void dfa_kernel_f(const float* __restrict__ value,
                  const int*   __restrict__ shapes,
                  const int*   __restrict__ starts,
                  const float* __restrict__ loc,
                  const float* __restrict__ attw,
                  float*       __restrict__ out,
                  int A, int per_cam)
{
    const int tid  = threadIdx.x;
    const int wv   = tid >> 6;
    const int lane = tid & 63;
    const int b = blockIdx.x / A;
    const int a = blockIdx.x - b * A;

    __shared__ int   sH[NLVL], sW[NLVL], sS[NLVL];
    __shared__ float red[NWAVES][EMB];
    if (tid < NLVL) {
        sH[tid] = shapes[tid * 2 + 0];
        sW[tid] = shapes[tid * 2 + 1];
        sS[tid] = starts[tid];
    }
    __syncthreads();

    int H_[NLVL], W_[NLVL], S_[NLVL];
    #pragma unroll
    for (int l = 0; l < NLVL; ++l) { H_[l] = sH[l]; W_[l] = sW[l]; S_[l] = sS[l]; }

    const int g = lane >> 3;
    const long ba = (long)b * A + a;
    const float* locp = loc  + ba * (NPTS * NCAMS * 2);
    const float* awp  = attw + ba * (NPTS * NCAMS * NLVL * NGROUPS) + g;

    float4 acc = make_float4(0.f, 0.f, 0.f, 0.f);
    float4 dA[16], dB[16];
    float  wA[16], wB[16];

    int j = wv;
    issue_pair_f(j, value, locp, awp, b, per_cam, lane, H_, W_, S_, dA, wA);
    j += NWAVES;
    while (j + NWAVES < NPAIR) {
        issue_pair_f(j, value, locp, awp, b, per_cam, lane, H_, W_, S_, dB, wB);
        consume_pair_f(dA, wA, acc);
        issue_pair_f(j + NWAVES, value, locp, awp, b, per_cam, lane, H_, W_, S_, dA, wA);
        consume_pair_f(dB, wB, acc);
        j += 2 * NWAVES;
    }
    if (j < NPAIR) {
        issue_pair_f(j, value, locp, awp, b, per_cam, lane, H_, W_, S_, dB, wB);
        consume_pair_f(dA, wA, acc);
        consume_pair_f(dB, wB, acc);
    } else {
        consume_pair_f(dA, wA, acc);
    }

    *(float4*)&red[wv][lane * 4] = acc;
    __syncthreads();

    float s0 = 0.f;
    if (tid < 256) {
        s0 = red[0][tid] + red[1][tid] + red[2][tid] + red[3][tid];
    } else {
        const int t = tid - 256;
        red[4][t] = red[4][t] + red[5][t] + red[6][t] + red[7][t];
    }
    __syncthreads();
    if (tid < 256) {
        out[ba * EMB + tid] = s0 + red[4][tid];
    }
}

extern "C" void kernel_launch(void* const* d_in, const int* in_sizes, int n_in,
                              void* d_out, int out_size, void* d_ws, size_t ws_size,
                              hipStream_t stream) {
    const float* value  = (const float*)d_in[0];
    const int*   shapes = (const int*)d_in[1];
    const int*   starts = (const int*)d_in[2];
    const float* loc    = (const float*)d_in[3];
    const float* attw   = (const float*)d_in[4];
    float*       out    = (float*)d_out;

    const int B = 2;
    const int A = out_size / (EMB * B);                  // 900
    const int per_cam = in_sizes[0] / (B * EMB * NCAMS); // 14960

    dim3 grid(B * A);
    dim3 block(512);

    const size_t need = (size_t)in_sizes[0] * sizeof(__half);  // ~92 MB
    if (ws_size >= need) {
        __half* hval = (__half*)d_ws;
        const int n4 = in_sizes[0] / 4;
        cvt_kernel<<<2048, 256, 0, stream>>>((const float4*)value, (ushort4*)hval, n4);
        dfa_kernel_h<<<grid, block, 0, stream>>>(hval, shapes, starts, loc, attw,
                                                 out, A, per_cam);
    } else {
        dfa_kernel_f<<<grid, block, 0, stream>>>(value, shapes, starts, loc, attw,
                                                 out, A, per_cam);
    }
}